// Round 4
// baseline (3782.623 us; speedup 1.0000x reference)
//
#include <hip/hip_runtime.h>
#include <stdint.h>

#define N_PTS 100000
#define NPAD  100032   // 32*3126, 64-divisible

typedef unsigned short u16;
typedef unsigned int   u32;
using bf16x8 = __attribute__((ext_vector_type(8))) short;
using f32x4  = __attribute__((ext_vector_type(4))) float;

__device__ __forceinline__ u16 f2bf(float f) {
    u32 u = __float_as_uint(f);
    u += 0x7FFFu + ((u >> 16) & 1u);   // RNE
    return (u16)(u >> 16);
}
__device__ __forceinline__ float bf2f(u16 h) {
    return __uint_as_float(((u32)h) << 16);
}

// ---------- padded transpose to bf16: dst[l][co][stride] = src[l][ci][co] (ci<R else 0)
__global__ __launch_bounds__(256) void k_transpose_pad(
    const float* __restrict__ src, u16* __restrict__ dst,
    int Lc, int R, int Cc, int stride) {
    int t = blockIdx.x * 256 + threadIdx.x;
    int total = Lc * Cc * stride;
    if (t >= total) return;
    int l = t / (Cc * stride);
    int rem = t - l * (Cc * stride);
    int co = rem / stride;
    int ci = rem - co * stride;
    dst[t] = (ci < R) ? f2bf(src[((size_t)l * R + ci) * Cc + co]) : (u16)0;
}

__global__ __launch_bounds__(256) void k_cast_bf16(
    const float* __restrict__ src, u16* __restrict__ dst, int total) {
    int t = blockIdx.x * 256 + threadIdx.x;
    if (t < total) dst[t] = f2bf(src[t]);
}

// ---------- PPF features
__device__ __forceinline__ float angf(float ax, float ay, float az,
                                      float bx, float by, float bz) {
    float cx = ay * bz - az * by;
    float cy = az * bx - ax * bz;
    float cz = ax * by - ay * bx;
    float cr = sqrtf(cx * cx + cy * cy + cz * cz);
    float dt = ax * bx + ay * by + az * bz;
    return atan2f(cr, dt);
}

__global__ __launch_bounds__(256) void k_ppf(
    const float* __restrict__ p, const float* __restrict__ nrm,
    const int* __restrict__ idx, const float* __restrict__ r,
    float* __restrict__ f5) {
    int t = blockIdx.x * 256 + threadIdx.x;
    if (t >= N_PTS * 16) return;
    int i = t >> 4, k = t & 15;
    int j = idx[(size_t)i * 32 + k];
    float pix = p[(size_t)i*3], piy = p[(size_t)i*3+1], piz = p[(size_t)i*3+2];
    float pjx = p[(size_t)j*3], pjy = p[(size_t)j*3+1], pjz = p[(size_t)j*3+2];
    float dx = pjx - pix, dy = pjy - piy, dz = pjz - piz;
    float dist = sqrtf(dx*dx + dy*dy + dz*dz);
    float nix = nrm[(size_t)i*3], niy = nrm[(size_t)i*3+1], niz = nrm[(size_t)i*3+2];
    float njx = nrm[(size_t)j*3], njy = nrm[(size_t)j*3+1], njz = nrm[(size_t)j*3+2];
    float a1 = angf(nix, niy, niz, dx, dy, dz);
    float a2 = angf(njx, njy, njz, dx, dy, dz);
    float a3 = angf(nix, niy, niz, njx, njy, njz);
    float rinv = 1.0f / r[0];
    float* o = f5 + (size_t)t * 5;
    o[0] = a1; o[1] = a2; o[2] = a3; o[3] = dist; o[4] = dist * rinv;
}

// ---------- neighbor stage v4: 16 pts/block, 512 thr (8 waves), wave = 2 pts.
// No B LDS staging (direct L2 reads); fused per-lane gather epilogue; 1 barrier.
// LDS 68.6 KB -> 2 blocks/CU (16 waves, 4/SIMD).
__global__ __launch_bounds__(512, 4) void k_neighbor(
    const float* __restrict__ xcur,
    const float* __restrict__ f5,
    const int*   __restrict__ idx,
    const u16*   __restrict__ w1pad,  // [256][32]
    const float* __restrict__ g1, const float* __restrict__ b1,
    const u16*   __restrict__ ew2t,   // [256][256] unpadded bf16
    const u16*   __restrict__ convbf, // [64][64]
    float*       __restrict__ pooled)
{
    __shared__ u16 swh[8][4224];      // 67,584 B: per-wave emb h-stage (16x264) / conv g (32x72)
    __shared__ int idxs[16][16];      // 1,024 B

    const int tid = threadIdx.x, w = tid >> 6, lane = tid & 63;
    const int rr = lane & 15, q = lane >> 4;
    const int i0 = blockIdx.x * 16;

    if (tid < 256)
        idxs[tid >> 4][tid & 15] = idx[(size_t)(i0 + (tid >> 4)) * 32 + (tid & 15)];

    u16* sw = &swh[w][0];
    bf16x8 afr[2][8];

    // ---- emb MLP per point: h = leaky(LN(f5pad @ w1)) -> A-frags in regs ----
    #pragma unroll
    for (int rt = 0; rt < 2; ++rt) {
        const int pt = i0 + 2 * w + rt;
        bf16x8 a1;
        #pragma unroll
        for (int e = 0; e < 8; ++e) a1[e] = 0;
        if (q == 0) {
            const float* fp = f5 + ((size_t)pt * 16 + rr) * 5;
            a1[0] = (short)f2bf(fp[0]); a1[1] = (short)f2bf(fp[1]);
            a1[2] = (short)f2bf(fp[2]); a1[3] = (short)f2bf(fp[3]);
            a1[4] = (short)f2bf(fp[4]);
        }
        f32x4 hacc[16];
        #pragma unroll
        for (int nt = 0; nt < 16; ++nt) {
            bf16x8 b = *(const bf16x8*)&w1pad[(nt * 16 + rr) * 32 + q * 8];
            f32x4 z = {0.f, 0.f, 0.f, 0.f};
            hacc[nt] = __builtin_amdgcn_mfma_f32_16x16x32_bf16(a1, b, z, 0, 0, 0);
        }
        float meanj[4], rstdj[4];
        #pragma unroll
        for (int j = 0; j < 4; ++j) {
            float s = 0.f, z2 = 0.f;
            #pragma unroll
            for (int nt = 0; nt < 16; ++nt) { float v = hacc[nt][j]; s += v; z2 += v * v; }
            s  += __shfl_xor(s, 1);  s  += __shfl_xor(s, 2);
            s  += __shfl_xor(s, 4);  s  += __shfl_xor(s, 8);
            z2 += __shfl_xor(z2, 1); z2 += __shfl_xor(z2, 2);
            z2 += __shfl_xor(z2, 4); z2 += __shfl_xor(z2, 8);
            float mean = s * (1.f / 256.f);
            float var = fmaxf(z2 * (1.f / 256.f) - mean * mean, 0.f);
            meanj[j] = mean;
            rstdj[j] = 1.0f / sqrtf(var + 1e-5f);
        }
        #pragma unroll
        for (int nt = 0; nt < 16; ++nt) {
            const int c = nt * 16 + rr;
            const float gg = g1[c], bb = b1[c];
            #pragma unroll
            for (int j = 0; j < 4; ++j) {
                float v = (hacc[nt][j] - meanj[j]) * rstdj[j] * gg + bb;
                v = v > 0.f ? v : 0.1f * v;
                sw[(4 * q + j) * 264 + c] = f2bf(v);
            }
        }
        #pragma unroll
        for (int kb = 0; kb < 8; ++kb)
            afr[rt][kb] = *(const bf16x8*)&sw[rr * 264 + kb * 32 + q * 8];
    }
    __syncthreads();   // idxs ready; sw reused for conv g-stage below

    int ixv[2][4];
    #pragma unroll
    for (int rt = 0; rt < 2; ++rt)
        #pragma unroll
        for (int j = 0; j < 4; ++j)
            ixv[rt][j] = idxs[2 * w + rt][4 * q + j];

    // ---- main GEMM: 16 col-tiles x 256 K, B direct from L2; fused gather epilogue ----
    #pragma unroll 2
    for (int nt = 0; nt < 16; ++nt) {
        const u16* bp = ew2t + (size_t)(nt * 16 + rr) * 256 + q * 8;
        bf16x8 bb[8];
        #pragma unroll
        for (int kb = 0; kb < 8; ++kb) bb[kb] = *(const bf16x8*)(bp + kb * 32);
        f32x4 a0 = {0.f,0.f,0.f,0.f}, a1v = {0.f,0.f,0.f,0.f};
        #pragma unroll
        for (int kb = 0; kb < 8; ++kb) {
            a0  = __builtin_amdgcn_mfma_f32_16x16x32_bf16(afr[0][kb], bb[kb], a0, 0, 0, 0);
            a1v = __builtin_amdgcn_mfma_f32_16x16x32_bf16(afr[1][kb], bb[kb], a1v, 0, 0, 0);
        }
        const int c = nt * 16 + rr;
        #pragma unroll
        for (int rt = 0; rt < 2; ++rt) {
            const f32x4 acc = rt ? a1v : a0;
            float gv0 = xcur[(size_t)ixv[rt][0] * 256 + c] + acc[0];
            float gv1 = xcur[(size_t)ixv[rt][1] * 256 + c] + acc[1];
            float gv2 = xcur[(size_t)ixv[rt][2] * 256 + c] + acc[2];
            float gv3 = xcur[(size_t)ixv[rt][3] * 256 + c] + acc[3];
            if (nt < 4) {
                // channels 0..63 feed the conv; transpose-stash g in LDS (bf16)
                sw[(rt * 16 + 4 * q + 0) * 72 + c] = f2bf(gv0);
                sw[(rt * 16 + 4 * q + 1) * 72 + c] = f2bf(gv1);
                sw[(rt * 16 + 4 * q + 2) * 72 + c] = f2bf(gv2);
                sw[(rt * 16 + 4 * q + 3) * 72 + c] = f2bf(gv3);
            } else {
                float m = fmaxf(fmaxf(gv0, gv1), fmaxf(gv2, gv3));
                m = fmaxf(m, __shfl_xor(m, 16));
                m = fmaxf(m, __shfl_xor(m, 32));
                if (lane < 16)
                    pooled[(size_t)(i0 + 2 * w + rt) * 256 + nt * 16 + lane] = m;
            }
        }
    }
    // ---- conv on g[:, :64] per point + pool (per-wave LDS, no barrier) ----
    #pragma unroll
    for (int rt = 0; rt < 2; ++rt) {
        const u16* gb = sw + rt * 16 * 72;
        bf16x8 a20 = *(const bf16x8*)&gb[rr * 72 + q * 8];
        bf16x8 a21 = *(const bf16x8*)&gb[rr * 72 + 32 + q * 8];
        #pragma unroll
        for (int cn = 0; cn < 4; ++cn) {
            f32x4 acc = {0.f, 0.f, 0.f, 0.f};
            bf16x8 b20 = *(const bf16x8*)&convbf[(cn * 16 + rr) * 64 + q * 8];
            bf16x8 b21 = *(const bf16x8*)&convbf[(cn * 16 + rr) * 64 + 32 + q * 8];
            acc = __builtin_amdgcn_mfma_f32_16x16x32_bf16(a20, b20, acc, 0, 0, 0);
            acc = __builtin_amdgcn_mfma_f32_16x16x32_bf16(a21, b21, acc, 0, 0, 0);
            float m = fmaxf(fmaxf(acc[0], acc[1]), fmaxf(acc[2], acc[3]));
            m = fmaxf(m, __shfl_xor(m, 16));
            m = fmaxf(m, __shfl_xor(m, 32));
            if (lane < 16)
                pooled[(size_t)(i0 + 2 * w + rt) * 256 + cn * 16 + lane] = m;
        }
    }
}

// ---------- pointwise v4: 32 rows/block, 512 thr, 8 waves split by COLUMN only.
__global__ __launch_bounds__(512, 4) void k_pointwise(
    const float* pool,
    const float* __restrict__ xres,
    float*       xnext,
    const u16*   __restrict__ b1t,     // [1024][256]
    const float* __restrict__ g1, const float* __restrict__ b1,
    const u16*   __restrict__ b2t,     // [256][1024]
    const float* __restrict__ g2, const float* __restrict__ b2,
    int guardRes)
{
    __shared__ u16 hm[32 * 1032];      // 66,048 B
    __shared__ float pst[32][8][2];

    const int tid = threadIdx.x, w = tid >> 6, lane = tid & 63;
    const int rr = lane & 15, q = lane >> 4;
    const size_t R0 = (size_t)blockIdx.x * 32;

    bf16x8 afr[2][8];
    #pragma unroll
    for (int rt = 0; rt < 2; ++rt) {
        int ar = (int)R0 + rt * 16 + rr; if (ar >= N_PTS) ar = N_PTS - 1;
        const float* arow = pool + (size_t)ar * 256;
        #pragma unroll
        for (int kb = 0; kb < 8; ++kb) {
            float4 f0 = *(const float4*)(arow + kb * 32 + q * 8);
            float4 f1 = *(const float4*)(arow + kb * 32 + q * 8 + 4);
            bf16x8 a;
            a[0] = (short)f2bf(f0.x); a[1] = (short)f2bf(f0.y);
            a[2] = (short)f2bf(f0.z); a[3] = (short)f2bf(f0.w);
            a[4] = (short)f2bf(f1.x); a[5] = (short)f2bf(f1.y);
            a[6] = (short)f2bf(f1.z); a[7] = (short)f2bf(f1.w);
            afr[rt][kb] = a;
        }
    }

    // ---- GEMM1: wave covers cols [w*128, w*128+128), all 32 rows ----
    #pragma unroll 2
    for (int ct = 0; ct < 8; ++ct) {
        const int co = w * 128 + ct * 16 + rr;
        const u16* bp = b1t + (size_t)co * 256 + q * 8;
        bf16x8 bb[8];
        #pragma unroll
        for (int kb = 0; kb < 8; ++kb) bb[kb] = *(const bf16x8*)(bp + kb * 32);
        f32x4 a0 = {0.f,0.f,0.f,0.f}, a1v = {0.f,0.f,0.f,0.f};
        #pragma unroll
        for (int kb = 0; kb < 8; ++kb) {
            a0  = __builtin_amdgcn_mfma_f32_16x16x32_bf16(afr[0][kb], bb[kb], a0, 0, 0, 0);
            a1v = __builtin_amdgcn_mfma_f32_16x16x32_bf16(afr[1][kb], bb[kb], a1v, 0, 0, 0);
        }
        #pragma unroll
        for (int j = 0; j < 4; ++j) {
            hm[(4 * q + j) * 1032 + co]        = f2bf(a0[j]);
            hm[(16 + 4 * q + j) * 1032 + co]   = f2bf(a1v[j]);
        }
    }
    __syncthreads();

    // ---- LN1 (read-back stats) + normalize + leaky ----
    {
        const int row = tid >> 4;       // 0..31
        const int t16 = tid & 15;
        u32* hm32 = (u32*)hm;
        const int base = row * 516;
        float s = 0.f, z = 0.f;
        #pragma unroll 8
        for (int e = 0; e < 32; ++e) {
            u32 pk = hm32[base + t16 + 16 * e];
            float v0 = bf2f((u16)(pk & 0xffffu)), v1 = bf2f((u16)(pk >> 16));
            s += v0 + v1; z += v0 * v0 + v1 * v1;
        }
        s += __shfl_xor(s, 1); s += __shfl_xor(s, 2);
        s += __shfl_xor(s, 4); s += __shfl_xor(s, 8);
        z += __shfl_xor(z, 1); z += __shfl_xor(z, 2);
        z += __shfl_xor(z, 4); z += __shfl_xor(z, 8);
        float mean = s * (1.f / 1024.f);
        float var = fmaxf(z * (1.f / 1024.f) - mean * mean, 0.f);
        float rstd = 1.0f / sqrtf(var + 1e-5f);
        #pragma unroll 4
        for (int e = 0; e < 32; ++e) {
            const int cidx = t16 + 16 * e;
            u32 pk = hm32[base + cidx];
            const int c = cidx * 2;
            float2 gg = *(const float2*)&g1[c];
            float2 bbv = *(const float2*)&b1[c];
            float v0 = (bf2f((u16)(pk & 0xffffu)) - mean) * rstd * gg.x + bbv.x;
            float v1 = (bf2f((u16)(pk >> 16))     - mean) * rstd * gg.y + bbv.y;
            v0 = v0 > 0.f ? v0 : 0.1f * v0;
            v1 = v1 > 0.f ? v1 : 0.1f * v1;
            hm32[base + cidx] = (u32)f2bf(v0) | ((u32)f2bf(v1) << 16);
        }
    }
    __syncthreads();

    // ---- GEMM2: wave covers out cols [w*32, w*32+32), K=1024 ----
    f32x4 acc2[2][2];
    #pragma unroll
    for (int ct = 0; ct < 2; ++ct) {
        const int cB = w * 32 + ct * 16 + rr;
        const u16* bp = b2t + (size_t)cB * 1024 + q * 8;
        f32x4 c0 = {0.f,0.f,0.f,0.f}, c1 = {0.f,0.f,0.f,0.f};
        #pragma unroll 8
        for (int kb = 0; kb < 32; ++kb) {
            bf16x8 b  = *(const bf16x8*)(bp + kb * 32);
            bf16x8 a0 = *(const bf16x8*)&hm[rr * 1032 + kb * 32 + q * 8];
            bf16x8 a1 = *(const bf16x8*)&hm[(16 + rr) * 1032 + kb * 32 + q * 8];
            c0 = __builtin_amdgcn_mfma_f32_16x16x32_bf16(a0, b, c0, 0, 0, 0);
            c1 = __builtin_amdgcn_mfma_f32_16x16x32_bf16(a1, b, c1, 0, 0, 0);
        }
        acc2[0][ct] = c0; acc2[1][ct] = c1;
    }

    // ---- LN2 partial stats -> pst ----
    #pragma unroll
    for (int rt = 0; rt < 2; ++rt) {
        #pragma unroll
        for (int j = 0; j < 4; ++j) {
            float s = acc2[rt][0][j] + acc2[rt][1][j];
            float z = acc2[rt][0][j] * acc2[rt][0][j] + acc2[rt][1][j] * acc2[rt][1][j];
            s += __shfl_xor(s, 1); s += __shfl_xor(s, 2);
            s += __shfl_xor(s, 4); s += __shfl_xor(s, 8);
            z += __shfl_xor(z, 1); z += __shfl_xor(z, 2);
            z += __shfl_xor(z, 4); z += __shfl_xor(z, 8);
            if (rr == 0) {
                pst[rt * 16 + 4 * q + j][w][0] = s;
                pst[rt * 16 + 4 * q + j][w][1] = z;
            }
        }
    }
    __syncthreads();

    // ---- LN2 finalize + residual + relu ----
    #pragma unroll
    for (int rt = 0; rt < 2; ++rt) {
        float mean2[4], rstd2[4];
        #pragma unroll
        for (int j = 0; j < 4; ++j) {
            const int row = rt * 16 + 4 * q + j;
            float s = 0.f, z = 0.f;
            #pragma unroll
            for (int k = 0; k < 8; ++k) { s += pst[row][k][0]; z += pst[row][k][1]; }
            float mean = s * (1.f / 256.f);
            float var = fmaxf(z * (1.f / 256.f) - mean * mean, 0.f);
            mean2[j] = mean;
            rstd2[j] = 1.0f / sqrtf(var + 1e-5f);
        }
        #pragma unroll
        for (int ct = 0; ct < 2; ++ct) {
            const int c = w * 32 + ct * 16 + rr;
            const float gg = g2[c], bb = b2[c];
            #pragma unroll
            for (int j = 0; j < 4; ++j) {
                const size_t row = R0 + rt * 16 + 4 * q + j;
                float v = (acc2[rt][ct][j] - mean2[j]) * rstd2[j] * gg + bb;
                float xv = 0.f;
                if (!guardRes || row < (size_t)N_PTS) xv = xres[row * 256 + c];
                float o = v + xv;
                xnext[row * 256 + c] = o > 0.f ? o : 0.f;
            }
        }
    }
}

// ---------- final projection: 128 rows/block, B staged in LDS halves
__global__ __launch_bounds__(512, 4) void k_proj(
    const float* __restrict__ xin,
    const u16*   __restrict__ pjtp,  // [256][264]
    const float* __restrict__ pb,
    float*       __restrict__ out)
{
    __shared__ u16 Bs[128 * 264];
    const int tid = threadIdx.x, w = tid >> 6, lane = tid & 63;
    const int rr = lane & 15, q = lane >> 4;
    const size_t R0 = (size_t)blockIdx.x * 128 + (size_t)w * 16;

    int arn = (int)R0 + rr; if (arn >= N_PTS) arn = N_PTS - 1;
    const float* arow = xin + (size_t)arn * 256;
    bf16x8 afr[8];
    #pragma unroll
    for (int kb = 0; kb < 8; ++kb) {
        float4 f0 = *(const float4*)(arow + kb * 32 + q * 8);
        float4 f1 = *(const float4*)(arow + kb * 32 + q * 8 + 4);
        bf16x8 a;
        a[0] = (short)f2bf(f0.x); a[1] = (short)f2bf(f0.y);
        a[2] = (short)f2bf(f0.z); a[3] = (short)f2bf(f0.w);
        a[4] = (short)f2bf(f1.x); a[5] = (short)f2bf(f1.y);
        a[6] = (short)f2bf(f1.z); a[7] = (short)f2bf(f1.w);
        afr[kb] = a;
    }
    #pragma unroll 1
    for (int h = 0; h < 2; ++h) {
        if (h) __syncthreads();
        for (int o = tid * 16; o < 67584; o += 8192)
            *(uint4*)((char*)Bs + o) = *(const uint4*)((const char*)(pjtp + h * 128 * 264) + o);
        __syncthreads();
        #pragma unroll 2
        for (int nt8 = 0; nt8 < 8; ++nt8) {
            f32x4 acc = {0.f, 0.f, 0.f, 0.f};
            #pragma unroll
            for (int kb = 0; kb < 8; ++kb) {
                bf16x8 b = *(const bf16x8*)&Bs[(nt8 * 16 + rr) * 264 + kb * 32 + q * 8];
                acc = __builtin_amdgcn_mfma_f32_16x16x32_bf16(afr[kb], b, acc, 0, 0, 0);
            }
            const int c = h * 128 + nt8 * 16 + rr;
            const float bias = pb[c];
            #pragma unroll
            for (int j = 0; j < 4; ++j) {
                const size_t row = R0 + 4 * q + j;
                if (row < (size_t)N_PTS) out[row * 256 + c] = acc[j] + bias;
            }
        }
    }
}

extern "C" void kernel_launch(void* const* d_in, const int* in_sizes, int n_in,
                              void* d_out, int out_size, void* d_ws, size_t ws_size,
                              hipStream_t stream) {
    const float* p      = (const float*)d_in[0];
    const float* x      = (const float*)d_in[1];
    const float* nn     = (const float*)d_in[2];
    const int*   idx    = (const int*)d_in[3];
    const float* r      = (const float*)d_in[4];
    const float* emb_w1 = (const float*)d_in[5];
    const float* emb_g1 = (const float*)d_in[6];
    const float* emb_b1 = (const float*)d_in[7];
    const float* emb_w2 = (const float*)d_in[8];
    const float* conv_w = (const float*)d_in[9];
    const float* pw_w1  = (const float*)d_in[10];
    const float* pw_g1  = (const float*)d_in[11];
    const float* pw_b1  = (const float*)d_in[12];
    const float* pw_w2  = (const float*)d_in[13];
    const float* pw_g2  = (const float*)d_in[14];
    const float* pw_b2  = (const float*)d_in[15];
    const float* proj_w = (const float*)d_in[16];
    const float* proj_b = (const float*)d_in[17];
    float* out = (float*)d_out;

    char* ws = (char*)d_ws;
    const size_t SZX = (size_t)NPAD * 256 * 4;
    float* P  = (float*)ws;
    float* X  = (float*)(ws + SZX);
    float* f5 = (float*)(ws + 2 * SZX);
    char*  wb = ws + 2 * SZX + (size_t)N_PTS * 16 * 5 * 4;
    u16* ew2t   = (u16*)wb;                       // [2][256][256] unpadded
    u16* pjtp   = ew2t + 2 * 256 * 256;           // [256][264]
    u16* w1pad  = pjtp + 256 * 264;               // [2][256][32]
    u16* convbf = w1pad + 2 * 256 * 32;           // [2][64][64]
    u16* b1t    = convbf + 2 * 64 * 64;           // [2][1024][256]
    u16* b2t    = b1t + 2 * 1024 * 256;           // [2][256][1024]

    k_transpose_pad<<<(2*256*256 + 255)/256, 256, 0, stream>>>(emb_w2, ew2t, 2, 256, 256, 256);
    k_transpose_pad<<<(256*264 + 255)/256, 256, 0, stream>>>(proj_w, pjtp, 1, 256, 256, 264);
    k_transpose_pad<<<(2*256*32 + 255)/256, 256, 0, stream>>>(emb_w1, w1pad, 2, 5, 256, 32);
    k_transpose_pad<<<(2*1024*256 + 255)/256, 256, 0, stream>>>(pw_w1, b1t, 2, 256, 1024, 256);
    k_transpose_pad<<<(2*256*1024 + 255)/256, 256, 0, stream>>>(pw_w2, b2t, 2, 1024, 256, 1024);
    k_cast_bf16<<<(2*64*64 + 255)/256, 256, 0, stream>>>(conv_w, convbf, 2*64*64);

    k_ppf<<<(N_PTS * 16 + 255)/256, 256, 0, stream>>>(p, nn, idx, r, f5);

    // layer 0
    k_neighbor<<<N_PTS/16, 512, 0, stream>>>(x, f5, idx, w1pad, emb_g1, emb_b1,
                                             ew2t, convbf, P);
    k_pointwise<<<NPAD/32, 512, 0, stream>>>(P, x, P, b1t, pw_g1, pw_b1,
                                             b2t, pw_g2, pw_b2, 1);
    // layer 1
    k_neighbor<<<N_PTS/16, 512, 0, stream>>>(P, f5, idx, w1pad + 256*32,
                                             emb_g1 + 256, emb_b1 + 256,
                                             ew2t + 256*256, convbf + 64*64, X);
    k_pointwise<<<NPAD/32, 512, 0, stream>>>(X, P, X, b1t + 1024*256,
                                             pw_g1 + 1024, pw_b1 + 1024,
                                             b2t + 256*1024, pw_g2 + 256, pw_b2 + 256, 0);
    // projection
    k_proj<<<(NPAD + 127)/128, 512, 0, stream>>>(X, pjtp, proj_b, out);
}

// Round 5
// 3567.591 us; speedup vs baseline: 1.0603x; 1.0603x over previous
//
#include <hip/hip_runtime.h>
#include <stdint.h>

#define N_PTS 100000
#define NPAD  100032   // 32*3126, 64-divisible

typedef unsigned short u16;
typedef unsigned int   u32;
using bf16x8 = __attribute__((ext_vector_type(8))) short;
using f32x4  = __attribute__((ext_vector_type(4))) float;

__device__ __forceinline__ u16 f2bf(float f) {
    u32 u = __float_as_uint(f);
    u += 0x7FFFu + ((u >> 16) & 1u);   // RNE
    return (u16)(u >> 16);
}
__device__ __forceinline__ float bf2f(u16 h) {
    return __uint_as_float(((u32)h) << 16);
}

// ---------- padded transpose to bf16: dst[l][co][stride] = src[l][ci][co] (ci<R else 0)
__global__ __launch_bounds__(256) void k_transpose_pad(
    const float* __restrict__ src, u16* __restrict__ dst,
    int Lc, int R, int Cc, int stride) {
    int t = blockIdx.x * 256 + threadIdx.x;
    int total = Lc * Cc * stride;
    if (t >= total) return;
    int l = t / (Cc * stride);
    int rem = t - l * (Cc * stride);
    int co = rem / stride;
    int ci = rem - co * stride;
    dst[t] = (ci < R) ? f2bf(src[((size_t)l * R + ci) * Cc + co]) : (u16)0;
}

__global__ __launch_bounds__(256) void k_cast_bf16(
    const float* __restrict__ src, u16* __restrict__ dst, int total) {
    int t = blockIdx.x * 256 + threadIdx.x;
    if (t < total) dst[t] = f2bf(src[t]);
}

// ---------- PPF features
__device__ __forceinline__ float angf(float ax, float ay, float az,
                                      float bx, float by, float bz) {
    float cx = ay * bz - az * by;
    float cy = az * bx - ax * bz;
    float cz = ax * by - ay * bx;
    float cr = sqrtf(cx * cx + cy * cy + cz * cz);
    float dt = ax * bx + ay * by + az * bz;
    return atan2f(cr, dt);
}

__global__ __launch_bounds__(256) void k_ppf(
    const float* __restrict__ p, const float* __restrict__ nrm,
    const int* __restrict__ idx, const float* __restrict__ r,
    float* __restrict__ f5) {
    int t = blockIdx.x * 256 + threadIdx.x;
    if (t >= N_PTS * 16) return;
    int i = t >> 4, k = t & 15;
    int j = idx[(size_t)i * 32 + k];
    float pix = p[(size_t)i*3], piy = p[(size_t)i*3+1], piz = p[(size_t)i*3+2];
    float pjx = p[(size_t)j*3], pjy = p[(size_t)j*3+1], pjz = p[(size_t)j*3+2];
    float dx = pjx - pix, dy = pjy - piy, dz = pjz - piz;
    float dist = sqrtf(dx*dx + dy*dy + dz*dz);
    float nix = nrm[(size_t)i*3], niy = nrm[(size_t)i*3+1], niz = nrm[(size_t)i*3+2];
    float njx = nrm[(size_t)j*3], njy = nrm[(size_t)j*3+1], njz = nrm[(size_t)j*3+2];
    float a1 = angf(nix, niy, niz, dx, dy, dz);
    float a2 = angf(njx, njy, njz, dx, dy, dz);
    float a3 = angf(nix, niy, niz, njx, njy, njz);
    float rinv = 1.0f / r[0];
    float* o = f5 + (size_t)t * 5;
    o[0] = a1; o[1] = a2; o[2] = a3; o[3] = dist; o[4] = dist * rinv;
}

// Build a swapped-GEMM B-fragment (h^T) from per-lane packed D-tiles.
// pk[t] holds cols t*16+4q+{0,1}|{2,3} for this lane's row n=rr.
// Target: element e = h[rr][kt*32 + q*8 + e].
__device__ __forceinline__ bf16x8 fixup_frag(const uint2* pk, int kt,
                                             int srcA, int srcB, bool hiT) {
    int aLx = __shfl((int)pk[2*kt].x,   srcA);
    int aHx = __shfl((int)pk[2*kt+1].x, srcA);
    int aLy = __shfl((int)pk[2*kt].y,   srcA);
    int aHy = __shfl((int)pk[2*kt+1].y, srcA);
    int bLx = __shfl((int)pk[2*kt].x,   srcB);
    int bHx = __shfl((int)pk[2*kt+1].x, srcB);
    int bLy = __shfl((int)pk[2*kt].y,   srcB);
    int bHy = __shfl((int)pk[2*kt+1].y, srcB);
    uint4 u;
    u.x = (u32)(hiT ? aHx : aLx);
    u.y = (u32)(hiT ? aHy : aLy);
    u.z = (u32)(hiT ? bHx : bLx);
    u.w = (u32)(hiT ? bHy : bLy);
    return *(bf16x8*)&u;
}

// ---------- neighbor stage v5: swapped-operand GEMMs, all-register transposes.
// 16 pts/block, 512 thr (8 waves), wave = 2 pts; LDS = Bs half + idxs = 68.6 KB
// -> 2 blocks/CU. pos stays fp32 in regs; pooling via shfl_xor over neighbor lanes.
__global__ __launch_bounds__(512, 4) void k_neighbor(
    const float* __restrict__ xcur,
    const float* __restrict__ f5,
    const int*   __restrict__ idx,
    const u16*   __restrict__ w1pad,  // [256][32]  (w1^T padded)
    const float* __restrict__ g1, const float* __restrict__ b1,
    const u16*   __restrict__ ew2tp,  // [256][264] (emb_w2^T padded)
    const u16*   __restrict__ convbf, // [64][64]
    float*       __restrict__ pooled)
{
    __shared__ u16 Bs[128 * 264];     // 67,584 B
    __shared__ int idxs[16][16];      // 1,024 B

    const int tid = threadIdx.x, w = tid >> 6, lane = tid & 63;
    const int rr = lane & 15, q = lane >> 4;
    const int i0 = blockIdx.x * 16;

    // stage Bs half 0 + idxs (overlaps with emb compute)
    for (int o = tid * 16; o < 67584; o += 8192)
        *(uint4*)((char*)Bs + o) = *(const uint4*)((const char*)ew2tp + o);
    if (tid < 256)
        idxs[tid >> 4][tid & 15] = idx[(size_t)(i0 + (tid >> 4)) * 32 + (tid & 15)];

    const int srcA = rr + ((q & 1) << 5);
    const int srcB = srcA + 16;
    const bool hiT = (q >> 1) != 0;

    // ---- emb (swapped): D'[c][n] = w1^T · f5^T ; lane holds h[n=rr][c=ct*16+4q+j].
    // LN over c in-lane + shfl_xor(16,32); pack; shuffle-fixup -> B2 frags (h^T).
    bf16x8 B2[2][8];
    #pragma unroll
    for (int rt = 0; rt < 2; ++rt) {
        const int pt = i0 + 2 * w + rt;
        bf16x8 a1;
        #pragma unroll
        for (int e = 0; e < 8; ++e) a1[e] = 0;
        if (q == 0) {
            const float* fp = f5 + ((size_t)pt * 16 + rr) * 5;
            a1[0] = (short)f2bf(fp[0]); a1[1] = (short)f2bf(fp[1]);
            a1[2] = (short)f2bf(fp[2]); a1[3] = (short)f2bf(fp[3]);
            a1[4] = (short)f2bf(fp[4]);
        }
        f32x4 hacc[16];
        #pragma unroll
        for (int ct = 0; ct < 16; ++ct) {
            bf16x8 aW = *(const bf16x8*)&w1pad[(ct * 16 + rr) * 32 + q * 8];
            f32x4 z = {0.f, 0.f, 0.f, 0.f};
            hacc[ct] = __builtin_amdgcn_mfma_f32_16x16x32_bf16(aW, a1, z, 0, 0, 0);
        }
        float s = 0.f, z2 = 0.f;
        #pragma unroll
        for (int ct = 0; ct < 16; ++ct) {
            #pragma unroll
            for (int j = 0; j < 4; ++j) { float v = hacc[ct][j]; s += v; z2 += v * v; }
        }
        s  += __shfl_xor(s, 16);  s  += __shfl_xor(s, 32);
        z2 += __shfl_xor(z2, 16); z2 += __shfl_xor(z2, 32);
        float mean = s * (1.f / 256.f);
        float var = fmaxf(z2 * (1.f / 256.f) - mean * mean, 0.f);
        float rstd = 1.0f / sqrtf(var + 1e-5f);

        uint2 pk[16];
        #pragma unroll
        for (int ct = 0; ct < 16; ++ct) {
            const int c0 = ct * 16 + 4 * q;
            float4 gg = *(const float4*)&g1[c0];
            float4 bb = *(const float4*)&b1[c0];
            float v0 = (hacc[ct][0] - mean) * rstd * gg.x + bb.x;
            float v1 = (hacc[ct][1] - mean) * rstd * gg.y + bb.y;
            float v2 = (hacc[ct][2] - mean) * rstd * gg.z + bb.z;
            float v3 = (hacc[ct][3] - mean) * rstd * gg.w + bb.w;
            v0 = v0 > 0.f ? v0 : 0.1f * v0;
            v1 = v1 > 0.f ? v1 : 0.1f * v1;
            v2 = v2 > 0.f ? v2 : 0.1f * v2;
            v3 = v3 > 0.f ? v3 : 0.1f * v3;
            pk[ct].x = (u32)f2bf(v0) | ((u32)f2bf(v1) << 16);
            pk[ct].y = (u32)f2bf(v2) | ((u32)f2bf(v3) << 16);
        }
        #pragma unroll
        for (int kt = 0; kt < 8; ++kt)
            B2[rt][kt] = fixup_frag(pk, kt, srcA, srcB, hiT);
    }
    __syncthreads();   // Bs half 0 + idxs ready

    const float* xr0 = xcur + (size_t)idxs[2 * w + 0][rr] * 256;
    const float* xr1 = xcur + (size_t)idxs[2 * w + 1][rr] * 256;
    float* pr0 = pooled + (size_t)(i0 + 2 * w + 0) * 256;
    float* pr1 = pooled + (size_t)(i0 + 2 * w + 1) * 256;

    uint2 gpk[2][4];   // conv staging (cols 0..63), packed bf16 in regs

    // ================= half 0: cols 0..127 =================
    #pragma unroll
    for (int nt = 0; nt < 8; ++nt) {
        const int cb = nt * 16 + 4 * q;
        float4 xg0 = *(const float4*)(xr0 + cb);
        float4 xg1 = *(const float4*)(xr1 + cb);
        f32x4 a0 = {0.f,0.f,0.f,0.f}, a1v = {0.f,0.f,0.f,0.f};
        #pragma unroll
        for (int kb = 0; kb < 8; ++kb) {
            bf16x8 bb = *(const bf16x8*)&Bs[(nt * 16 + rr) * 264 + kb * 32 + q * 8];
            a0  = __builtin_amdgcn_mfma_f32_16x16x32_bf16(bb, B2[0][kb], a0, 0, 0, 0);
            a1v = __builtin_amdgcn_mfma_f32_16x16x32_bf16(bb, B2[1][kb], a1v, 0, 0, 0);
        }
        f32x4 g0 = {a0[0]+xg0.x, a0[1]+xg0.y, a0[2]+xg0.z, a0[3]+xg0.w};
        f32x4 g1v = {a1v[0]+xg1.x, a1v[1]+xg1.y, a1v[2]+xg1.z, a1v[3]+xg1.w};
        if (nt < 4) {
            gpk[0][nt].x = (u32)f2bf(g0[0]) | ((u32)f2bf(g0[1]) << 16);
            gpk[0][nt].y = (u32)f2bf(g0[2]) | ((u32)f2bf(g0[3]) << 16);
            gpk[1][nt].x = (u32)f2bf(g1v[0]) | ((u32)f2bf(g1v[1]) << 16);
            gpk[1][nt].y = (u32)f2bf(g1v[2]) | ((u32)f2bf(g1v[3]) << 16);
        } else {
            #pragma unroll
            for (int mk = 1; mk <= 8; mk <<= 1) {
                g0[0] = fmaxf(g0[0], __shfl_xor(g0[0], mk));
                g0[1] = fmaxf(g0[1], __shfl_xor(g0[1], mk));
                g0[2] = fmaxf(g0[2], __shfl_xor(g0[2], mk));
                g0[3] = fmaxf(g0[3], __shfl_xor(g0[3], mk));
                g1v[0] = fmaxf(g1v[0], __shfl_xor(g1v[0], mk));
                g1v[1] = fmaxf(g1v[1], __shfl_xor(g1v[1], mk));
                g1v[2] = fmaxf(g1v[2], __shfl_xor(g1v[2], mk));
                g1v[3] = fmaxf(g1v[3], __shfl_xor(g1v[3], mk));
            }
            if (rr == 0) {
                *(float4*)(pr0 + cb) = make_float4(g0[0], g0[1], g0[2], g0[3]);
                *(float4*)(pr1 + cb) = make_float4(g1v[0], g1v[1], g1v[2], g1v[3]);
            }
        }
    }
    __syncthreads();   // all waves done reading Bs half 0

    // issue half-1 staging (overlaps conv below)
    for (int o = tid * 16; o < 67584; o += 8192)
        *(uint4*)((char*)Bs + o) = *(const uint4*)((const char*)(ew2tp + 128 * 264) + o);

    // ---- conv (swapped): g1[n][d], B-frag = g^T via fixup; pool over n-lanes ----
    #pragma unroll
    for (int rt = 0; rt < 2; ++rt) {
        bf16x8 Bc0 = fixup_frag(gpk[rt], 0, srcA, srcB, hiT);
        bf16x8 Bc1 = fixup_frag(gpk[rt], 1, srcA, srcB, hiT);
        float* pr = rt ? pr1 : pr0;
        #pragma unroll
        for (int cn = 0; cn < 4; ++cn) {
            bf16x8 cA0 = *(const bf16x8*)&convbf[(cn * 16 + rr) * 64 + q * 8];
            bf16x8 cA1 = *(const bf16x8*)&convbf[(cn * 16 + rr) * 64 + 32 + q * 8];
            f32x4 z = {0.f,0.f,0.f,0.f};
            f32x4 acc = __builtin_amdgcn_mfma_f32_16x16x32_bf16(cA0, Bc0, z, 0, 0, 0);
            acc = __builtin_amdgcn_mfma_f32_16x16x32_bf16(cA1, Bc1, acc, 0, 0, 0);
            #pragma unroll
            for (int mk = 1; mk <= 8; mk <<= 1) {
                acc[0] = fmaxf(acc[0], __shfl_xor(acc[0], mk));
                acc[1] = fmaxf(acc[1], __shfl_xor(acc[1], mk));
                acc[2] = fmaxf(acc[2], __shfl_xor(acc[2], mk));
                acc[3] = fmaxf(acc[3], __shfl_xor(acc[3], mk));
            }
            if (rr == 0)
                *(float4*)(pr + cn * 16 + 4 * q) = make_float4(acc[0], acc[1], acc[2], acc[3]);
        }
    }
    __syncthreads();   // Bs half 1 ready

    // ================= half 1: cols 128..255 =================
    #pragma unroll
    for (int nt = 0; nt < 8; ++nt) {
        const int cb = 128 + nt * 16 + 4 * q;
        float4 xg0 = *(const float4*)(xr0 + cb);
        float4 xg1 = *(const float4*)(xr1 + cb);
        f32x4 a0 = {0.f,0.f,0.f,0.f}, a1v = {0.f,0.f,0.f,0.f};
        #pragma unroll
        for (int kb = 0; kb < 8; ++kb) {
            bf16x8 bb = *(const bf16x8*)&Bs[(nt * 16 + rr) * 264 + kb * 32 + q * 8];
            a0  = __builtin_amdgcn_mfma_f32_16x16x32_bf16(bb, B2[0][kb], a0, 0, 0, 0);
            a1v = __builtin_amdgcn_mfma_f32_16x16x32_bf16(bb, B2[1][kb], a1v, 0, 0, 0);
        }
        f32x4 g0 = {a0[0]+xg0.x, a0[1]+xg0.y, a0[2]+xg0.z, a0[3]+xg0.w};
        f32x4 g1v = {a1v[0]+xg1.x, a1v[1]+xg1.y, a1v[2]+xg1.z, a1v[3]+xg1.w};
        #pragma unroll
        for (int mk = 1; mk <= 8; mk <<= 1) {
            g0[0] = fmaxf(g0[0], __shfl_xor(g0[0], mk));
            g0[1] = fmaxf(g0[1], __shfl_xor(g0[1], mk));
            g0[2] = fmaxf(g0[2], __shfl_xor(g0[2], mk));
            g0[3] = fmaxf(g0[3], __shfl_xor(g0[3], mk));
            g1v[0] = fmaxf(g1v[0], __shfl_xor(g1v[0], mk));
            g1v[1] = fmaxf(g1v[1], __shfl_xor(g1v[1], mk));
            g1v[2] = fmaxf(g1v[2], __shfl_xor(g1v[2], mk));
            g1v[3] = fmaxf(g1v[3], __shfl_xor(g1v[3], mk));
        }
        if (rr == 0) {
            *(float4*)(pr0 + cb) = make_float4(g0[0], g0[1], g0[2], g0[3]);
            *(float4*)(pr1 + cb) = make_float4(g1v[0], g1v[1], g1v[2], g1v[3]);
        }
    }
}

// ---------- pointwise v4: 32 rows/block, 512 thr, 8 waves split by COLUMN only.
__global__ __launch_bounds__(512, 4) void k_pointwise(
    const float* pool,
    const float* __restrict__ xres,
    float*       xnext,
    const u16*   __restrict__ b1t,     // [1024][256]
    const float* __restrict__ g1, const float* __restrict__ b1,
    const u16*   __restrict__ b2t,     // [256][1024]
    const float* __restrict__ g2, const float* __restrict__ b2,
    int guardRes)
{
    __shared__ u16 hm[32 * 1032];      // 66,048 B
    __shared__ float pst[32][8][2];

    const int tid = threadIdx.x, w = tid >> 6, lane = tid & 63;
    const int rr = lane & 15, q = lane >> 4;
    const size_t R0 = (size_t)blockIdx.x * 32;

    bf16x8 afr[2][8];
    #pragma unroll
    for (int rt = 0; rt < 2; ++rt) {
        int ar = (int)R0 + rt * 16 + rr; if (ar >= N_PTS) ar = N_PTS - 1;
        const float* arow = pool + (size_t)ar * 256;
        #pragma unroll
        for (int kb = 0; kb < 8; ++kb) {
            float4 f0 = *(const float4*)(arow + kb * 32 + q * 8);
            float4 f1 = *(const float4*)(arow + kb * 32 + q * 8 + 4);
            bf16x8 a;
            a[0] = (short)f2bf(f0.x); a[1] = (short)f2bf(f0.y);
            a[2] = (short)f2bf(f0.z); a[3] = (short)f2bf(f0.w);
            a[4] = (short)f2bf(f1.x); a[5] = (short)f2bf(f1.y);
            a[6] = (short)f2bf(f1.z); a[7] = (short)f2bf(f1.w);
            afr[rt][kb] = a;
        }
    }

    // ---- GEMM1: wave covers cols [w*128, w*128+128), all 32 rows ----
    #pragma unroll 2
    for (int ct = 0; ct < 8; ++ct) {
        const int co = w * 128 + ct * 16 + rr;
        const u16* bp = b1t + (size_t)co * 256 + q * 8;
        bf16x8 bb[8];
        #pragma unroll
        for (int kb = 0; kb < 8; ++kb) bb[kb] = *(const bf16x8*)(bp + kb * 32);
        f32x4 a0 = {0.f,0.f,0.f,0.f}, a1v = {0.f,0.f,0.f,0.f};
        #pragma unroll
        for (int kb = 0; kb < 8; ++kb) {
            a0  = __builtin_amdgcn_mfma_f32_16x16x32_bf16(afr[0][kb], bb[kb], a0, 0, 0, 0);
            a1v = __builtin_amdgcn_mfma_f32_16x16x32_bf16(afr[1][kb], bb[kb], a1v, 0, 0, 0);
        }
        #pragma unroll
        for (int j = 0; j < 4; ++j) {
            hm[(4 * q + j) * 1032 + co]        = f2bf(a0[j]);
            hm[(16 + 4 * q + j) * 1032 + co]   = f2bf(a1v[j]);
        }
    }
    __syncthreads();

    // ---- LN1 (read-back stats) + normalize + leaky ----
    {
        const int row = tid >> 4;       // 0..31
        const int t16 = tid & 15;
        u32* hm32 = (u32*)hm;
        const int base = row * 516;
        float s = 0.f, z = 0.f;
        #pragma unroll 8
        for (int e = 0; e < 32; ++e) {
            u32 pk = hm32[base + t16 + 16 * e];
            float v0 = bf2f((u16)(pk & 0xffffu)), v1 = bf2f((u16)(pk >> 16));
            s += v0 + v1; z += v0 * v0 + v1 * v1;
        }
        s += __shfl_xor(s, 1); s += __shfl_xor(s, 2);
        s += __shfl_xor(s, 4); s += __shfl_xor(s, 8);
        z += __shfl_xor(z, 1); z += __shfl_xor(z, 2);
        z += __shfl_xor(z, 4); z += __shfl_xor(z, 8);
        float mean = s * (1.f / 1024.f);
        float var = fmaxf(z * (1.f / 1024.f) - mean * mean, 0.f);
        float rstd = 1.0f / sqrtf(var + 1e-5f);
        #pragma unroll 4
        for (int e = 0; e < 32; ++e) {
            const int cidx = t16 + 16 * e;
            u32 pk = hm32[base + cidx];
            const int c = cidx * 2;
            float2 gg = *(const float2*)&g1[c];
            float2 bbv = *(const float2*)&b1[c];
            float v0 = (bf2f((u16)(pk & 0xffffu)) - mean) * rstd * gg.x + bbv.x;
            float v1 = (bf2f((u16)(pk >> 16))     - mean) * rstd * gg.y + bbv.y;
            v0 = v0 > 0.f ? v0 : 0.1f * v0;
            v1 = v1 > 0.f ? v1 : 0.1f * v1;
            hm32[base + cidx] = (u32)f2bf(v0) | ((u32)f2bf(v1) << 16);
        }
    }
    __syncthreads();

    // ---- GEMM2: wave covers out cols [w*32, w*32+32), K=1024 ----
    f32x4 acc2[2][2];
    #pragma unroll
    for (int ct = 0; ct < 2; ++ct) {
        const int cB = w * 32 + ct * 16 + rr;
        const u16* bp = b2t + (size_t)cB * 1024 + q * 8;
        f32x4 c0 = {0.f,0.f,0.f,0.f}, c1 = {0.f,0.f,0.f,0.f};
        #pragma unroll 8
        for (int kb = 0; kb < 32; ++kb) {
            bf16x8 b  = *(const bf16x8*)(bp + kb * 32);
            bf16x8 a0 = *(const bf16x8*)&hm[rr * 1032 + kb * 32 + q * 8];
            bf16x8 a1 = *(const bf16x8*)&hm[(16 + rr) * 1032 + kb * 32 + q * 8];
            c0 = __builtin_amdgcn_mfma_f32_16x16x32_bf16(a0, b, c0, 0, 0, 0);
            c1 = __builtin_amdgcn_mfma_f32_16x16x32_bf16(a1, b, c1, 0, 0, 0);
        }
        acc2[0][ct] = c0; acc2[1][ct] = c1;
    }

    // ---- LN2 partial stats -> pst ----
    #pragma unroll
    for (int rt = 0; rt < 2; ++rt) {
        #pragma unroll
        for (int j = 0; j < 4; ++j) {
            float s = acc2[rt][0][j] + acc2[rt][1][j];
            float z = acc2[rt][0][j] * acc2[rt][0][j] + acc2[rt][1][j] * acc2[rt][1][j];
            s += __shfl_xor(s, 1); s += __shfl_xor(s, 2);
            s += __shfl_xor(s, 4); s += __shfl_xor(s, 8);
            z += __shfl_xor(z, 1); z += __shfl_xor(z, 2);
            z += __shfl_xor(z, 4); z += __shfl_xor(z, 8);
            if (rr == 0) {
                pst[rt * 16 + 4 * q + j][w][0] = s;
                pst[rt * 16 + 4 * q + j][w][1] = z;
            }
        }
    }
    __syncthreads();

    // ---- LN2 finalize + residual + relu ----
    #pragma unroll
    for (int rt = 0; rt < 2; ++rt) {
        float mean2[4], rstd2[4];
        #pragma unroll
        for (int j = 0; j < 4; ++j) {
            const int row = rt * 16 + 4 * q + j;
            float s = 0.f, z = 0.f;
            #pragma unroll
            for (int k = 0; k < 8; ++k) { s += pst[row][k][0]; z += pst[row][k][1]; }
            float mean = s * (1.f / 256.f);
            float var = fmaxf(z * (1.f / 256.f) - mean * mean, 0.f);
            mean2[j] = mean;
            rstd2[j] = 1.0f / sqrtf(var + 1e-5f);
        }
        #pragma unroll
        for (int ct = 0; ct < 2; ++ct) {
            const int c = w * 32 + ct * 16 + rr;
            const float gg = g2[c], bb = b2[c];
            #pragma unroll
            for (int j = 0; j < 4; ++j) {
                const size_t row = R0 + rt * 16 + 4 * q + j;
                float v = (acc2[rt][ct][j] - mean2[j]) * rstd2[j] * gg + bb;
                float xv = 0.f;
                if (!guardRes || row < (size_t)N_PTS) xv = xres[row * 256 + c];
                float o = v + xv;
                xnext[row * 256 + c] = o > 0.f ? o : 0.f;
            }
        }
    }
}

// ---------- final projection: 128 rows/block, B staged in LDS halves
__global__ __launch_bounds__(512, 4) void k_proj(
    const float* __restrict__ xin,
    const u16*   __restrict__ pjtp,  // [256][264]
    const float* __restrict__ pb,
    float*       __restrict__ out)
{
    __shared__ u16 Bs[128 * 264];
    const int tid = threadIdx.x, w = tid >> 6, lane = tid & 63;
    const int rr = lane & 15, q = lane >> 4;
    const size_t R0 = (size_t)blockIdx.x * 128 + (size_t)w * 16;

    int arn = (int)R0 + rr; if (arn >= N_PTS) arn = N_PTS - 1;
    const float* arow = xin + (size_t)arn * 256;
    bf16x8 afr[8];
    #pragma unroll
    for (int kb = 0; kb < 8; ++kb) {
        float4 f0 = *(const float4*)(arow + kb * 32 + q * 8);
        float4 f1 = *(const float4*)(arow + kb * 32 + q * 8 + 4);
        bf16x8 a;
        a[0] = (short)f2bf(f0.x); a[1] = (short)f2bf(f0.y);
        a[2] = (short)f2bf(f0.z); a[3] = (short)f2bf(f0.w);
        a[4] = (short)f2bf(f1.x); a[5] = (short)f2bf(f1.y);
        a[6] = (short)f2bf(f1.z); a[7] = (short)f2bf(f1.w);
        afr[kb] = a;
    }
    #pragma unroll 1
    for (int h = 0; h < 2; ++h) {
        if (h) __syncthreads();
        for (int o = tid * 16; o < 67584; o += 8192)
            *(uint4*)((char*)Bs + o) = *(const uint4*)((const char*)(pjtp + h * 128 * 264) + o);
        __syncthreads();
        #pragma unroll 2
        for (int nt8 = 0; nt8 < 8; ++nt8) {
            f32x4 acc = {0.f, 0.f, 0.f, 0.f};
            #pragma unroll
            for (int kb = 0; kb < 8; ++kb) {
                bf16x8 b = *(const bf16x8*)&Bs[(nt8 * 16 + rr) * 264 + kb * 32 + q * 8];
                acc = __builtin_amdgcn_mfma_f32_16x16x32_bf16(afr[kb], b, acc, 0, 0, 0);
            }
            const int c = h * 128 + nt8 * 16 + rr;
            const float bias = pb[c];
            #pragma unroll
            for (int j = 0; j < 4; ++j) {
                const size_t row = R0 + 4 * q + j;
                if (row < (size_t)N_PTS) out[row * 256 + c] = acc[j] + bias;
            }
        }
    }
}

extern "C" void kernel_launch(void* const* d_in, const int* in_sizes, int n_in,
                              void* d_out, int out_size, void* d_ws, size_t ws_size,
                              hipStream_t stream) {
    const float* p      = (const float*)d_in[0];
    const float* x      = (const float*)d_in[1];
    const float* nn     = (const float*)d_in[2];
    const int*   idx    = (const int*)d_in[3];
    const float* r      = (const float*)d_in[4];
    const float* emb_w1 = (const float*)d_in[5];
    const float* emb_g1 = (const float*)d_in[6];
    const float* emb_b1 = (const float*)d_in[7];
    const float* emb_w2 = (const float*)d_in[8];
    const float* conv_w = (const float*)d_in[9];
    const float* pw_w1  = (const float*)d_in[10];
    const float* pw_g1  = (const float*)d_in[11];
    const float* pw_b1  = (const float*)d_in[12];
    const float* pw_w2  = (const float*)d_in[13];
    const float* pw_g2  = (const float*)d_in[14];
    const float* pw_b2  = (const float*)d_in[15];
    const float* proj_w = (const float*)d_in[16];
    const float* proj_b = (const float*)d_in[17];
    float* out = (float*)d_out;

    char* ws = (char*)d_ws;
    const size_t SZX = (size_t)NPAD * 256 * 4;
    float* P  = (float*)ws;
    float* X  = (float*)(ws + SZX);
    float* f5 = (float*)(ws + 2 * SZX);
    char*  wb = ws + 2 * SZX + (size_t)N_PTS * 16 * 5 * 4;
    u16* ew2tp  = (u16*)wb;                       // [2][256][264]
    u16* pjtp   = ew2tp + 2 * 256 * 264;          // [256][264]
    u16* w1pad  = pjtp + 256 * 264;               // [2][256][32]
    u16* convbf = w1pad + 2 * 256 * 32;           // [2][64][64]
    u16* b1t    = convbf + 2 * 64 * 64;           // [2][1024][256]
    u16* b2t    = b1t + 2 * 1024 * 256;           // [2][256][1024]

    k_transpose_pad<<<(2*256*264 + 255)/256, 256, 0, stream>>>(emb_w2, ew2tp, 2, 256, 256, 264);
    k_transpose_pad<<<(256*264 + 255)/256, 256, 0, stream>>>(proj_w, pjtp, 1, 256, 256, 264);
    k_transpose_pad<<<(2*256*32 + 255)/256, 256, 0, stream>>>(emb_w1, w1pad, 2, 5, 256, 32);
    k_transpose_pad<<<(2*1024*256 + 255)/256, 256, 0, stream>>>(pw_w1, b1t, 2, 256, 1024, 256);
    k_transpose_pad<<<(2*256*1024 + 255)/256, 256, 0, stream>>>(pw_w2, b2t, 2, 1024, 256, 1024);
    k_cast_bf16<<<(2*64*64 + 255)/256, 256, 0, stream>>>(conv_w, convbf, 2*64*64);

    k_ppf<<<(N_PTS * 16 + 255)/256, 256, 0, stream>>>(p, nn, idx, r, f5);

    // layer 0
    k_neighbor<<<N_PTS/16, 512, 0, stream>>>(x, f5, idx, w1pad, emb_g1, emb_b1,
                                             ew2tp, convbf, P);
    k_pointwise<<<NPAD/32, 512, 0, stream>>>(P, x, P, b1t, pw_g1, pw_b1,
                                             b2t, pw_g2, pw_b2, 1);
    // layer 1
    k_neighbor<<<N_PTS/16, 512, 0, stream>>>(P, f5, idx, w1pad + 256*32,
                                             emb_g1 + 256, emb_b1 + 256,
                                             ew2tp + 256*264, convbf + 64*64, X);
    k_pointwise<<<NPAD/32, 512, 0, stream>>>(X, P, X, b1t + 1024*256,
                                             pw_g1 + 1024, pw_b1 + 1024,
                                             b2t + 256*1024, pw_g2 + 256, pw_b2 + 256, 0);
    // projection
    k_proj<<<(NPAD + 127)/128, 512, 0, stream>>>(X, pjtp, proj_b, out);
}